// Round 3
// baseline (74.908 us; speedup 1.0000x reference)
//
#include <hip/hip_runtime.h>
#include <hip/hip_fp16.h>
#include <math.h>

#define NB 8          // NUM_BINS
#define DD 32         // D
constexpr float TB   = 10.0f;   // TAIL_BOUND
constexpr float MBW  = 1e-3f;   // MIN_BIN_WIDTH
constexpr float MBH  = 1e-3f;   // MIN_BIN_HEIGHT
constexpr float MDER = 1e-3f;   // MIN_DERIVATIVE

__device__ __forceinline__ float softplusf(float v) {
    return (v > 20.0f) ? v : log1pf(expf(v));
}

__global__ __launch_bounds__(256) void mfb_kernel(
    const float* __restrict__ x,
    const float* __restrict__ uw,
    const float* __restrict__ uh,
    const float* __restrict__ ud,
    float* __restrict__ out,
    int total2)
{
    // Packed per-(dim,bin) record: {cw f32, invw f32, half2(ch,h), half2(d0,d1)}
    // Row stride 9 (not 8) => bank quad of entry (d,b) = (d+b)%8 : free spread
    // of data-dependent bin gathers across bank quads (no XOR op needed).
    __shared__ float4 s_T[DD][NB + 1];
    __shared__ float  s_kn[DD][7];

    const int t = threadIdx.x;

    if (t < DD) {
        float posw[NB + 1], posh[NB + 1], dv[NB + 1];
        // ---- widths ----
        {
            float u[NB];
            float m = -1e30f;
            #pragma unroll
            for (int k = 0; k < NB; ++k) { u[k] = uw[t * NB + k]; m = fmaxf(m, u[k]); }
            float s = 0.0f;
            #pragma unroll
            for (int k = 0; k < NB; ++k) { u[k] = expf(u[k] - m); s += u[k]; }
            const float inv = 1.0f / s;
            posw[0] = -TB;
            float cum = 0.0f;
            #pragma unroll
            for (int k = 0; k < NB; ++k) {
                cum += MBW + (1.0f - MBW * (float)NB) * (u[k] * inv);
                posw[k + 1] = 2.0f * TB * cum - TB;
            }
            posw[NB] = TB;
        }
        // ---- heights ----
        {
            float u[NB];
            float m = -1e30f;
            #pragma unroll
            for (int k = 0; k < NB; ++k) { u[k] = uh[t * NB + k]; m = fmaxf(m, u[k]); }
            float s = 0.0f;
            #pragma unroll
            for (int k = 0; k < NB; ++k) { u[k] = expf(u[k] - m); s += u[k]; }
            const float inv = 1.0f / s;
            posh[0] = -TB;
            float cum = 0.0f;
            #pragma unroll
            for (int k = 0; k < NB; ++k) {
                cum += MBH + (1.0f - MBH * (float)NB) * (u[k] * inv);
                posh[k + 1] = 2.0f * TB * cum - TB;
            }
            posh[NB] = TB;
        }
        // ---- derivatives ----
        {
            const float c   = logf(expm1f(1.0f - MDER));
            const float bnd = MDER + softplusf(c);   // == 1.0 to fp precision
            dv[0]  = bnd;
            dv[NB] = bnd;
            #pragma unroll
            for (int k = 1; k < NB; ++k)
                dv[k] = MDER + softplusf(ud[t * (NB - 1) + (k - 1)]);
        }
        // ---- publish ----
        #pragma unroll
        for (int k = 0; k < 7; ++k) s_kn[t][k] = posw[k + 1];
        #pragma unroll
        for (int b = 0; b < NB; ++b) {
            const float w    = posw[b + 1] - posw[b];
            const float h    = posh[b + 1] - posh[b];
            const float invw = 1.0f / w;
            const unsigned u1 = ((unsigned)__half_as_ushort(__float2half_rn(h)) << 16)
                              |  (unsigned)__half_as_ushort(__float2half_rn(posh[b]));
            const unsigned u2 = ((unsigned)__half_as_ushort(__float2half_rn(dv[b + 1])) << 16)
                              |  (unsigned)__half_as_ushort(__float2half_rn(dv[b]));
            float4 T;
            T.x = posw[b];
            T.y = invw;
            T.z = __uint_as_float(u1);
            T.w = __uint_as_float(u2);
            s_T[t][b] = T;
        }
    }
    __syncthreads();

    constexpr float HALF_LOG_2PI = 0.91893853320467274178f;

    const int g      = blockIdx.x * blockDim.x + t;
    const int stride = gridDim.x * blockDim.x;
    // stride*2 % 32 == 0 -> each thread's dim pair is fixed across iterations
    const int dbase  = (g * 2) & (DD - 1);

    // 14 named scalar knots: pinned in VGPRs by the asm below (the round-2
    // kernel's 28-float knot array was rematerialized from LDS every element:
    // VGPR_Count=32 proved it).
    float a0 = s_kn[dbase][0], a1 = s_kn[dbase][1], a2 = s_kn[dbase][2],
          a3 = s_kn[dbase][3], a4 = s_kn[dbase][4], a5 = s_kn[dbase][5],
          a6 = s_kn[dbase][6];
    float b0 = s_kn[dbase + 1][0], b1 = s_kn[dbase + 1][1], b2 = s_kn[dbase + 1][2],
          b3 = s_kn[dbase + 1][3], b4 = s_kn[dbase + 1][4], b5 = s_kn[dbase + 1][5],
          b6 = s_kn[dbase + 1][6];
    const float4* __restrict__ rowA = s_T[dbase];
    const float4* __restrict__ rowB = s_T[dbase + 1];

    auto evalone = [&](float xx,
                       float k0, float k1, float k2, float k3, float k4, float k5, float k6,
                       const float4* __restrict__ row) -> float {
        const float xc = fminf(fmaxf(xx, -TB), TB);
        int idx = 0;
        idx += (xc >= k0) ? 1 : 0;
        idx += (xc >= k1) ? 1 : 0;
        idx += (xc >= k2) ? 1 : 0;
        idx += (xc >= k3) ? 1 : 0;
        idx += (xc >= k4) ? 1 : 0;
        idx += (xc >= k5) ? 1 : 0;
        idx += (xc >= k6) ? 1 : 0;

        const float4 T = row[idx];
        const unsigned u1 = __float_as_uint(T.z);
        const unsigned u2 = __float_as_uint(T.w);
        const float ch = __half2float(__ushort_as_half((unsigned short)(u1 & 0xffffu)));
        const float h  = __half2float(__ushort_as_half((unsigned short)(u1 >> 16)));
        const float d0 = __half2float(__ushort_as_half((unsigned short)(u2 & 0xffffu)));
        const float d1 = __half2float(__ushort_as_half((unsigned short)(u2 >> 16)));

        const float delta = h * T.y;
        const float twod  = delta + delta;
        const float s2    = (d0 + d1) - twod;
        const float theta = (xc - T.x) * T.y;
        const float tt    = theta * theta;
        const float omt   = 1.0f - theta;
        const float t1m   = theta * omt;
        const float denom = fmaf(s2, t1m, delta);
        const float rden  = __builtin_amdgcn_rcpf(denom);
        const float zin   = fmaf(h * fmaf(delta, tt, d0 * t1m), rden, ch);
        const float p     = fmaf(d1, tt, fmaf(twod, t1m, d0 * (omt * omt)));
        const float ld    = __logf(((delta * delta) * p) * (rden * rden));
        // outside [-B,B]: z=x identity; logdet at clamped boundary evaluates to
        // log(1.0 +- eps) ~ 0, so no select needed on ld (error << threshold)
        const float z = (fabsf(xx) <= TB) ? zin : xx;
        return fmaf(z * z, -0.5f, ld) - HALF_LOG_2PI;
    };

    const float2* __restrict__ x2 = reinterpret_cast<const float2*>(x);
    float2* __restrict__ o2 = reinterpret_cast<float2*>(out);

    int i = g;
    for (; i + stride < total2; i += 2 * stride) {
        // zero-cost pin: knots must live in VGPRs across the loop body
        asm volatile("" : "+v"(a0), "+v"(a1), "+v"(a2), "+v"(a3), "+v"(a4),
                          "+v"(a5), "+v"(a6),
                          "+v"(b0), "+v"(b1), "+v"(b2), "+v"(b3), "+v"(b4),
                          "+v"(b5), "+v"(b6));
        const float2 va = x2[i];
        const float2 vb = x2[i + stride];
        float2 ra, rb;
        ra.x = evalone(va.x, a0, a1, a2, a3, a4, a5, a6, rowA);
        ra.y = evalone(va.y, b0, b1, b2, b3, b4, b5, b6, rowB);
        rb.x = evalone(vb.x, a0, a1, a2, a3, a4, a5, a6, rowA);
        rb.y = evalone(vb.y, b0, b1, b2, b3, b4, b5, b6, rowB);
        o2[i] = ra;
        o2[i + stride] = rb;
    }
    for (; i < total2; i += stride) {
        const float2 va = x2[i];
        float2 ra;
        ra.x = evalone(va.x, a0, a1, a2, a3, a4, a5, a6, rowA);
        ra.y = evalone(va.y, b0, b1, b2, b3, b4, b5, b6, rowB);
        o2[i] = ra;
    }
}

extern "C" void kernel_launch(void* const* d_in, const int* in_sizes, int n_in,
                              void* d_out, int out_size, void* d_ws, size_t ws_size,
                              hipStream_t stream) {
    const float* x  = (const float*)d_in[0];
    const float* uw = (const float*)d_in[1];
    const float* uh = (const float*)d_in[2];
    const float* ud = (const float*)d_in[3];
    float* out = (float*)d_out;

    const int total2 = in_sizes[0] / 2;             // N*D/2 float2 elements
    int blocks = (total2 + 255) / 256;
    if (blocks > 2048) blocks = 2048;

    mfb_kernel<<<blocks, 256, 0, stream>>>(x, uw, uh, ud, out, total2);
}

// Round 4
// 69.412 us; speedup vs baseline: 1.0792x; 1.0792x over previous
//
#include <hip/hip_runtime.h>
#include <hip/hip_fp16.h>
#include <math.h>

#define NB 8          // NUM_BINS
#define DD 32         // D
constexpr float TB   = 10.0f;   // TAIL_BOUND
constexpr float MBW  = 1e-3f;   // MIN_BIN_WIDTH
constexpr float MBH  = 1e-3f;   // MIN_BIN_HEIGHT
constexpr float MDER = 1e-3f;   // MIN_DERIVATIVE

__device__ __forceinline__ float softplusf(float v) {
    return (v > 20.0f) ? v : log1pf(expf(v));
}

__global__ __launch_bounds__(256) void mfb_kernel(
    const float* __restrict__ x,
    const float* __restrict__ uw,
    const float* __restrict__ uh,
    const float* __restrict__ ud,
    float* __restrict__ out,
    int n4)
{
    // Packed per-(dim,bin) record: {cw f32, invw f32, half2(ch,h), half2(d0,d1)}
    // Row stride 9 float4 (padding) + XOR-on-bin swizzle (key=(d>>2)&7) to
    // decorrelate data-dependent bin gathers across dims sharing a bank base.
    __shared__ float4 s_T[DD][NB + 1];
    __shared__ float  s_kn[DD][7];

    const int t = threadIdx.x;

    if (t < DD) {
        float posw[NB + 1], posh[NB + 1], dv[NB + 1];
        // ---- widths ----
        {
            float u[NB];
            float m = -1e30f;
            #pragma unroll
            for (int k = 0; k < NB; ++k) { u[k] = uw[t * NB + k]; m = fmaxf(m, u[k]); }
            float s = 0.0f;
            #pragma unroll
            for (int k = 0; k < NB; ++k) { u[k] = expf(u[k] - m); s += u[k]; }
            const float inv = 1.0f / s;
            posw[0] = -TB;
            float cum = 0.0f;
            #pragma unroll
            for (int k = 0; k < NB; ++k) {
                cum += MBW + (1.0f - MBW * (float)NB) * (u[k] * inv);
                posw[k + 1] = 2.0f * TB * cum - TB;
            }
            posw[NB] = TB;
        }
        // ---- heights ----
        {
            float u[NB];
            float m = -1e30f;
            #pragma unroll
            for (int k = 0; k < NB; ++k) { u[k] = uh[t * NB + k]; m = fmaxf(m, u[k]); }
            float s = 0.0f;
            #pragma unroll
            for (int k = 0; k < NB; ++k) { u[k] = expf(u[k] - m); s += u[k]; }
            const float inv = 1.0f / s;
            posh[0] = -TB;
            float cum = 0.0f;
            #pragma unroll
            for (int k = 0; k < NB; ++k) {
                cum += MBH + (1.0f - MBH * (float)NB) * (u[k] * inv);
                posh[k + 1] = 2.0f * TB * cum - TB;
            }
            posh[NB] = TB;
        }
        // ---- derivatives ----
        {
            const float c   = logf(expm1f(1.0f - MDER));
            const float bnd = MDER + softplusf(c);   // == 1.0 to fp precision
            dv[0]  = bnd;
            dv[NB] = bnd;
            #pragma unroll
            for (int k = 1; k < NB; ++k)
                dv[k] = MDER + softplusf(ud[t * (NB - 1) + (k - 1)]);
        }
        // ---- publish ----
        #pragma unroll
        for (int k = 0; k < 7; ++k) s_kn[t][k] = posw[k + 1];
        const int key = (t >> 2) & 7;
        #pragma unroll
        for (int b = 0; b < NB; ++b) {
            const float w    = posw[b + 1] - posw[b];
            const float h    = posh[b + 1] - posh[b];
            const float invw = 1.0f / w;
            const unsigned u1 = ((unsigned)__half_as_ushort(__float2half_rn(h)) << 16)
                              |  (unsigned)__half_as_ushort(__float2half_rn(posh[b]));
            const unsigned u2 = ((unsigned)__half_as_ushort(__float2half_rn(dv[b + 1])) << 16)
                              |  (unsigned)__half_as_ushort(__float2half_rn(dv[b]));
            float4 T;
            T.x = posw[b];
            T.y = invw;
            T.z = __uint_as_float(u1);
            T.w = __uint_as_float(u2);
            s_T[t][b ^ key] = T;
        }
    }
    __syncthreads();

    constexpr float HALF_LOG_2PI = 0.91893853320467274178f;

    const int g      = blockIdx.x * blockDim.x + t;
    const int stride = gridDim.x * blockDim.x;
    // stride*4 % 32 == 0 -> each thread's dim quad is fixed across iterations
    const int dbase  = (g * 4) & (DD - 1);
    const int key    = (dbase >> 2) & 7;

    // 28 named scalar knots, pinned in VGPRs by the in-loop asm (round-2's
    // array version was rematerialized from LDS: VGPR_Count=32 proved it;
    // round-3's named-scalar pin worked: VGPR_Count=28).
    float a0 = s_kn[dbase + 0][0], a1 = s_kn[dbase + 0][1], a2 = s_kn[dbase + 0][2],
          a3 = s_kn[dbase + 0][3], a4 = s_kn[dbase + 0][4], a5 = s_kn[dbase + 0][5],
          a6 = s_kn[dbase + 0][6];
    float b0 = s_kn[dbase + 1][0], b1 = s_kn[dbase + 1][1], b2 = s_kn[dbase + 1][2],
          b3 = s_kn[dbase + 1][3], b4 = s_kn[dbase + 1][4], b5 = s_kn[dbase + 1][5],
          b6 = s_kn[dbase + 1][6];
    float c0 = s_kn[dbase + 2][0], c1 = s_kn[dbase + 2][1], c2 = s_kn[dbase + 2][2],
          c3 = s_kn[dbase + 2][3], c4 = s_kn[dbase + 2][4], c5 = s_kn[dbase + 2][5],
          c6 = s_kn[dbase + 2][6];
    float e0 = s_kn[dbase + 3][0], e1 = s_kn[dbase + 3][1], e2 = s_kn[dbase + 3][2],
          e3 = s_kn[dbase + 3][3], e4 = s_kn[dbase + 3][4], e5 = s_kn[dbase + 3][5],
          e6 = s_kn[dbase + 3][6];

    const float4* __restrict__ row0 = s_T[dbase + 0];
    const float4* __restrict__ row1 = s_T[dbase + 1];
    const float4* __restrict__ row2 = s_T[dbase + 2];
    const float4* __restrict__ row3 = s_T[dbase + 3];

    auto evalone = [&](float xx,
                       float k0, float k1, float k2, float k3, float k4, float k5, float k6,
                       const float4* __restrict__ row) -> float {
        const float xc = fminf(fmaxf(xx, -TB), TB);
        int idx = 0;
        idx += (xc >= k0) ? 1 : 0;
        idx += (xc >= k1) ? 1 : 0;
        idx += (xc >= k2) ? 1 : 0;
        idx += (xc >= k3) ? 1 : 0;
        idx += (xc >= k4) ? 1 : 0;
        idx += (xc >= k5) ? 1 : 0;
        idx += (xc >= k6) ? 1 : 0;

        const float4 T = row[idx ^ key];
        const unsigned u1 = __float_as_uint(T.z);
        const unsigned u2 = __float_as_uint(T.w);
        const float ch = __half2float(__ushort_as_half((unsigned short)(u1 & 0xffffu)));
        const float h  = __half2float(__ushort_as_half((unsigned short)(u1 >> 16)));
        const float d0 = __half2float(__ushort_as_half((unsigned short)(u2 & 0xffffu)));
        const float d1 = __half2float(__ushort_as_half((unsigned short)(u2 >> 16)));

        const float delta = h * T.y;
        const float twod  = delta + delta;
        const float s2    = (d0 + d1) - twod;
        const float theta = (xc - T.x) * T.y;
        const float tt    = theta * theta;
        const float omt   = 1.0f - theta;
        const float t1m   = theta * omt;
        const float denom = fmaf(s2, t1m, delta);
        const float rden  = __builtin_amdgcn_rcpf(denom);
        const float zin   = fmaf(h * fmaf(delta, tt, d0 * t1m), rden, ch);
        const float p     = fmaf(d1, tt, fmaf(twod, t1m, d0 * (omt * omt)));
        const float ld    = __logf(((delta * delta) * p) * (rden * rden));
        // outside [-B,B]: z=x identity; at the clamped boundary ld evaluates
        // to log(1 +- eps) ~ 0, so no select needed on ld
        const float z = (fabsf(xx) <= TB) ? zin : xx;
        return fmaf(z * z, -0.5f, ld) - HALF_LOG_2PI;
    };

    const float4* __restrict__ x4 = reinterpret_cast<const float4*>(x);
    float4* __restrict__ o4 = reinterpret_cast<float4*>(out);

    for (int i = g; i < n4; i += stride) {
        // zero-cost pin: knots must stay VGPR-resident across the loop body
        asm volatile("" : "+v"(a0), "+v"(a1), "+v"(a2), "+v"(a3), "+v"(a4),
                          "+v"(a5), "+v"(a6),
                          "+v"(b0), "+v"(b1), "+v"(b2), "+v"(b3), "+v"(b4),
                          "+v"(b5), "+v"(b6));
        asm volatile("" : "+v"(c0), "+v"(c1), "+v"(c2), "+v"(c3), "+v"(c4),
                          "+v"(c5), "+v"(c6),
                          "+v"(e0), "+v"(e1), "+v"(e2), "+v"(e3), "+v"(e4),
                          "+v"(e5), "+v"(e6));
        const float4 xv = x4[i];
        float4 r;
        r.x = evalone(xv.x, a0, a1, a2, a3, a4, a5, a6, row0);
        r.y = evalone(xv.y, b0, b1, b2, b3, b4, b5, b6, row1);
        r.z = evalone(xv.z, c0, c1, c2, c3, c4, c5, c6, row2);
        r.w = evalone(xv.w, e0, e1, e2, e3, e4, e5, e6, row3);
        o4[i] = r;
    }
}

extern "C" void kernel_launch(void* const* d_in, const int* in_sizes, int n_in,
                              void* d_out, int out_size, void* d_ws, size_t ws_size,
                              hipStream_t stream) {
    const float* x  = (const float*)d_in[0];
    const float* uw = (const float*)d_in[1];
    const float* uh = (const float*)d_in[2];
    const float* ud = (const float*)d_in[3];
    float* out = (float*)d_out;

    const int n4 = in_sizes[0] / 4;                 // N*D/4 float4 elements
    int blocks = (n4 + 255) / 256;
    if (blocks > 2048) blocks = 2048;

    mfb_kernel<<<blocks, 256, 0, stream>>>(x, uw, uh, ud, out, n4);
}

// Round 5
// 60.327 us; speedup vs baseline: 1.2417x; 1.1506x over previous
//
#include <hip/hip_runtime.h>
#include <math.h>

#define NB 8          // NUM_BINS
#define DD 32         // D
constexpr float TB   = 10.0f;   // TAIL_BOUND
constexpr float MBW  = 1e-3f;   // MIN_BIN_WIDTH
constexpr float MBH  = 1e-3f;   // MIN_BIN_HEIGHT
constexpr float MDER = 1e-3f;   // MIN_DERIVATIVE

__device__ __forceinline__ float softplusf(float v) {
    return (v > 20.0f) ? v : log1pf(expf(v));
}

__global__ __launch_bounds__(256, 4) void mfb_kernel(
    const float* __restrict__ x,
    const float* __restrict__ uw,
    const float* __restrict__ uh,
    const float* __restrict__ ud,
    float* __restrict__ out,
    int n4)
{
    // 32B per-(dim,bin) record, all f32, Horner-ready:
    //   W0 = {m=invw, b=-cw*invw, A=h*(delta-d0), B=h*d0}
    //   W1 = {ch, delta, s2=d0+d1-2delta, d0}
    // Row stride 17 float4s (odd) rotates bank quads across dims; bin index
    // XOR-swizzled by key=(d>>2)&7 to spread data-dependent gathers.
    __shared__ float4 s_T[DD][2 * NB + 1];
    __shared__ float  s_kn[DD][7];

    const int t = threadIdx.x;

    if (t < DD) {
        float posw[NB + 1], posh[NB + 1], dv[NB + 1];
        // ---- widths ----
        {
            float u[NB];
            float m = -1e30f;
            #pragma unroll
            for (int k = 0; k < NB; ++k) { u[k] = uw[t * NB + k]; m = fmaxf(m, u[k]); }
            float s = 0.0f;
            #pragma unroll
            for (int k = 0; k < NB; ++k) { u[k] = expf(u[k] - m); s += u[k]; }
            const float inv = 1.0f / s;
            posw[0] = -TB;
            float cum = 0.0f;
            #pragma unroll
            for (int k = 0; k < NB; ++k) {
                cum += MBW + (1.0f - MBW * (float)NB) * (u[k] * inv);
                posw[k + 1] = 2.0f * TB * cum - TB;
            }
            posw[NB] = TB;
        }
        // ---- heights ----
        {
            float u[NB];
            float m = -1e30f;
            #pragma unroll
            for (int k = 0; k < NB; ++k) { u[k] = uh[t * NB + k]; m = fmaxf(m, u[k]); }
            float s = 0.0f;
            #pragma unroll
            for (int k = 0; k < NB; ++k) { u[k] = expf(u[k] - m); s += u[k]; }
            const float inv = 1.0f / s;
            posh[0] = -TB;
            float cum = 0.0f;
            #pragma unroll
            for (int k = 0; k < NB; ++k) {
                cum += MBH + (1.0f - MBH * (float)NB) * (u[k] * inv);
                posh[k + 1] = 2.0f * TB * cum - TB;
            }
            posh[NB] = TB;
        }
        // ---- derivatives ----
        {
            const float c   = logf(expm1f(1.0f - MDER));
            const float bnd = MDER + softplusf(c);   // == 1.0 to fp precision
            dv[0]  = bnd;
            dv[NB] = bnd;
            #pragma unroll
            for (int k = 1; k < NB; ++k)
                dv[k] = MDER + softplusf(ud[t * (NB - 1) + (k - 1)]);
        }
        // ---- publish ----
        #pragma unroll
        for (int k = 0; k < 7; ++k) s_kn[t][k] = posw[k + 1];
        const int key = (t >> 2) & 7;
        #pragma unroll
        for (int b = 0; b < NB; ++b) {
            const float w     = posw[b + 1] - posw[b];
            const float h     = posh[b + 1] - posh[b];
            const float invw  = 1.0f / w;
            const float delta = h * invw;
            const float d0    = dv[b];
            const float d1    = dv[b + 1];
            const float s2    = (d0 + d1) - 2.0f * delta;
            const int   bb    = b ^ key;
            s_T[t][2 * bb]     = make_float4(invw, -posw[b] * invw,
                                             h * (delta - d0), h * d0);
            s_T[t][2 * bb + 1] = make_float4(posh[b], delta, s2, d0);
        }
    }
    __syncthreads();

    constexpr float HALF_LOG_2PI = 0.91893853320467274178f;
    constexpr float LN2          = 0.69314718055994530942f;

    const int g      = blockIdx.x * blockDim.x + t;
    const int stride = gridDim.x * blockDim.x;
    // stride*4 % 32 == 0 -> each thread's dim quad is fixed across iterations
    const int dbase  = (g * 4) & (DD - 1);
    const int key    = (dbase >> 2) & 7;

    // 28 named scalar knots. No in-loop asm pin this time (round 4 showed the
    // pins serialize the schedule); launch_bounds(256,4) gives the allocator
    // a 128-VGPR budget so these stay resident without rematerialization.
    float a0 = s_kn[dbase + 0][0], a1 = s_kn[dbase + 0][1], a2 = s_kn[dbase + 0][2],
          a3 = s_kn[dbase + 0][3], a4 = s_kn[dbase + 0][4], a5 = s_kn[dbase + 0][5],
          a6 = s_kn[dbase + 0][6];
    float b0 = s_kn[dbase + 1][0], b1 = s_kn[dbase + 1][1], b2 = s_kn[dbase + 1][2],
          b3 = s_kn[dbase + 1][3], b4 = s_kn[dbase + 1][4], b5 = s_kn[dbase + 1][5],
          b6 = s_kn[dbase + 1][6];
    float c0 = s_kn[dbase + 2][0], c1 = s_kn[dbase + 2][1], c2 = s_kn[dbase + 2][2],
          c3 = s_kn[dbase + 2][3], c4 = s_kn[dbase + 2][4], c5 = s_kn[dbase + 2][5],
          c6 = s_kn[dbase + 2][6];
    float e0 = s_kn[dbase + 3][0], e1 = s_kn[dbase + 3][1], e2 = s_kn[dbase + 3][2],
          e3 = s_kn[dbase + 3][3], e4 = s_kn[dbase + 3][4], e5 = s_kn[dbase + 3][5],
          e6 = s_kn[dbase + 3][6];

    const float4* __restrict__ r0 = &s_T[dbase + 0][0];
    const float4* __restrict__ r1 = &s_T[dbase + 1][0];
    const float4* __restrict__ r2 = &s_T[dbase + 2][0];
    const float4* __restrict__ r3 = &s_T[dbase + 3][0];

    auto evalone = [&](float xx,
                       float k0, float k1, float k2, float k3, float k4, float k5, float k6,
                       const float4* __restrict__ row) -> float {
        // bin search on raw x (clamp is off this path; idx saturates correctly)
        int idx = 0;
        idx += (xx >= k0) ? 1 : 0;
        idx += (xx >= k1) ? 1 : 0;
        idx += (xx >= k2) ? 1 : 0;
        idx += (xx >= k3) ? 1 : 0;
        idx += (xx >= k4) ? 1 : 0;
        idx += (xx >= k5) ? 1 : 0;
        idx += (xx >= k6) ? 1 : 0;

        const float4* p = row + 2 * (idx ^ key);
        const float4 W0 = p[0];   // {m, b, A, B}
        const float4 W1 = p[1];   // {ch, delta, s2, d0}  (ds_read offset:16)

        const float xc    = fminf(fmaxf(xx, -TB), TB);   // v_med3
        const float theta = fmaf(xc, W0.x, W0.y);
        const float u     = fmaf(-theta, theta, theta);            // θ(1-θ)
        const float den   = fmaf(W1.z, u, W1.y);
        const float rden  = __builtin_amdgcn_rcpf(den);
        const float num1  = theta * fmaf(theta, W0.z, W0.w);       // h(δθ²+d0θ(1-θ))
        const float zin   = fmaf(num1, rden, W1.x);
        const float dmd   = W1.y - W1.w;                           // δ-d0
        const float poly  = fmaf(fmaf(W1.z, theta, dmd + dmd), theta, W1.w);
        const float ee    = W1.y * rden;                           // δ/den
        const float larg  = poly * (ee * ee);
        const float lg2   = __log2f(larg);
        // outside [-B,B]: θ∈{0,1} exactly -> larg = boundary deriv = 1 -> lg2≈0
        const float z  = (fabsf(xx) <= TB) ? zin : xx;
        const float ld = fmaf(lg2, LN2, -HALF_LOG_2PI);
        return fmaf(z * z, -0.5f, ld);
    };

    const float4* __restrict__ x4 = reinterpret_cast<const float4*>(x);
    float4* __restrict__ o4 = reinterpret_cast<float4*>(out);

    int i = g;
    for (; i + stride < n4; i += 2 * stride) {
        const float4 xa = x4[i];
        const float4 xb = x4[i + stride];
        float4 ra, rb;
        ra.x = evalone(xa.x, a0, a1, a2, a3, a4, a5, a6, r0);
        ra.y = evalone(xa.y, b0, b1, b2, b3, b4, b5, b6, r1);
        ra.z = evalone(xa.z, c0, c1, c2, c3, c4, c5, c6, r2);
        ra.w = evalone(xa.w, e0, e1, e2, e3, e4, e5, e6, r3);
        rb.x = evalone(xb.x, a0, a1, a2, a3, a4, a5, a6, r0);
        rb.y = evalone(xb.y, b0, b1, b2, b3, b4, b5, b6, r1);
        rb.z = evalone(xb.z, c0, c1, c2, c3, c4, c5, c6, r2);
        rb.w = evalone(xb.w, e0, e1, e2, e3, e4, e5, e6, r3);
        o4[i] = ra;
        o4[i + stride] = rb;
    }
    for (; i < n4; i += stride) {
        const float4 xa = x4[i];
        float4 ra;
        ra.x = evalone(xa.x, a0, a1, a2, a3, a4, a5, a6, r0);
        ra.y = evalone(xa.y, b0, b1, b2, b3, b4, b5, b6, r1);
        ra.z = evalone(xa.z, c0, c1, c2, c3, c4, c5, c6, r2);
        ra.w = evalone(xa.w, e0, e1, e2, e3, e4, e5, e6, r3);
        o4[i] = ra;
    }
}

extern "C" void kernel_launch(void* const* d_in, const int* in_sizes, int n_in,
                              void* d_out, int out_size, void* d_ws, size_t ws_size,
                              hipStream_t stream) {
    const float* x  = (const float*)d_in[0];
    const float* uw = (const float*)d_in[1];
    const float* uh = (const float*)d_in[2];
    const float* ud = (const float*)d_in[3];
    float* out = (float*)d_out;

    const int n4 = in_sizes[0] / 4;                 // N*D/4 float4 elements
    int blocks = (n4 + 255) / 256;
    if (blocks > 2048) blocks = 2048;

    mfb_kernel<<<blocks, 256, 0, stream>>>(x, uw, uh, ud, out, n4);
}

// Round 6
// 59.057 us; speedup vs baseline: 1.2684x; 1.0215x over previous
//
#include <hip/hip_runtime.h>
#include <hip/hip_fp16.h>
#include <math.h>

#define NB 8          // NUM_BINS
#define DD 32         // D
constexpr float TB   = 10.0f;   // TAIL_BOUND
constexpr float MBW  = 1e-3f;   // MIN_BIN_WIDTH
constexpr float MBH  = 1e-3f;   // MIN_BIN_HEIGHT
constexpr float MDER = 1e-3f;   // MIN_DERIVATIVE

__device__ __forceinline__ float softplusf(float v) {
    return (v > 20.0f) ? v : log1pf(expf(v));
}

__global__ __launch_bounds__(256, 4) void mfb_kernel(
    const float* __restrict__ x,
    const float* __restrict__ uw,
    const float* __restrict__ uh,
    const float* __restrict__ ud,
    float* __restrict__ out,
    int n4)
{
    // 16B per-(dim,bin) record -> ONE ds_read_b128 per element:
    //   { m=invw f32, b=-cw*invw f32, half2(ch,h), half2(d0,d1) }
    // delta/A/B/s2 derived in registers (VALU has idle headroom; the LDS
    // pipe does not: round 5's 2x32B reads pushed conflicts 2.6e6 -> 9.8e6).
    // Row stride 9 float4s + XOR-on-bin key=(d>>2)&7: round 4 measured 2.6e6
    // conflict cycles with this exact layout.
    __shared__ float4 s_T[DD][NB + 1];
    __shared__ float  s_kn[DD][7];

    const int t = threadIdx.x;

    if (t < DD) {
        float posw[NB + 1], posh[NB + 1], dv[NB + 1];
        // ---- widths ----
        {
            float u[NB];
            float m = -1e30f;
            #pragma unroll
            for (int k = 0; k < NB; ++k) { u[k] = uw[t * NB + k]; m = fmaxf(m, u[k]); }
            float s = 0.0f;
            #pragma unroll
            for (int k = 0; k < NB; ++k) { u[k] = expf(u[k] - m); s += u[k]; }
            const float inv = 1.0f / s;
            posw[0] = -TB;
            float cum = 0.0f;
            #pragma unroll
            for (int k = 0; k < NB; ++k) {
                cum += MBW + (1.0f - MBW * (float)NB) * (u[k] * inv);
                posw[k + 1] = 2.0f * TB * cum - TB;
            }
            posw[NB] = TB;
        }
        // ---- heights ----
        {
            float u[NB];
            float m = -1e30f;
            #pragma unroll
            for (int k = 0; k < NB; ++k) { u[k] = uh[t * NB + k]; m = fmaxf(m, u[k]); }
            float s = 0.0f;
            #pragma unroll
            for (int k = 0; k < NB; ++k) { u[k] = expf(u[k] - m); s += u[k]; }
            const float inv = 1.0f / s;
            posh[0] = -TB;
            float cum = 0.0f;
            #pragma unroll
            for (int k = 0; k < NB; ++k) {
                cum += MBH + (1.0f - MBH * (float)NB) * (u[k] * inv);
                posh[k + 1] = 2.0f * TB * cum - TB;
            }
            posh[NB] = TB;
        }
        // ---- derivatives ----
        {
            const float c   = logf(expm1f(1.0f - MDER));
            const float bnd = MDER + softplusf(c);   // == 1.0 to fp precision
            dv[0]  = bnd;
            dv[NB] = bnd;
            #pragma unroll
            for (int k = 1; k < NB; ++k)
                dv[k] = MDER + softplusf(ud[t * (NB - 1) + (k - 1)]);
        }
        // ---- publish ----
        #pragma unroll
        for (int k = 0; k < 7; ++k) s_kn[t][k] = posw[k + 1];
        const int key = (t >> 2) & 7;
        #pragma unroll
        for (int b = 0; b < NB; ++b) {
            const float w    = posw[b + 1] - posw[b];
            const float invw = 1.0f / w;
            const unsigned u1 = ((unsigned)__half_as_ushort(__float2half_rn(posh[b + 1] - posh[b])) << 16)
                              |  (unsigned)__half_as_ushort(__float2half_rn(posh[b]));
            const unsigned u2 = ((unsigned)__half_as_ushort(__float2half_rn(dv[b + 1])) << 16)
                              |  (unsigned)__half_as_ushort(__float2half_rn(dv[b]));
            float4 T;
            T.x = invw;
            T.y = -posw[b] * invw;
            T.z = __uint_as_float(u1);
            T.w = __uint_as_float(u2);
            s_T[t][b ^ key] = T;
        }
    }
    __syncthreads();

    constexpr float HALF_LOG_2PI = 0.91893853320467274178f;
    constexpr float LN2          = 0.69314718055994530942f;

    const int g      = blockIdx.x * blockDim.x + t;
    const int stride = gridDim.x * blockDim.x;
    // stride*4 % 32 == 0 -> each thread's dim quad is fixed across iterations
    const int dbase  = (g * 4) & (DD - 1);
    const int key    = (dbase >> 2) & 7;

    // 28 named scalar knots; launch_bounds(256,4) gives the allocator a
    // 128-VGPR budget so they stay resident (no in-loop asm pins: round 4
    // showed those serialize the schedule).
    float a0 = s_kn[dbase + 0][0], a1 = s_kn[dbase + 0][1], a2 = s_kn[dbase + 0][2],
          a3 = s_kn[dbase + 0][3], a4 = s_kn[dbase + 0][4], a5 = s_kn[dbase + 0][5],
          a6 = s_kn[dbase + 0][6];
    float b0 = s_kn[dbase + 1][0], b1 = s_kn[dbase + 1][1], b2 = s_kn[dbase + 1][2],
          b3 = s_kn[dbase + 1][3], b4 = s_kn[dbase + 1][4], b5 = s_kn[dbase + 1][5],
          b6 = s_kn[dbase + 1][6];
    float c0 = s_kn[dbase + 2][0], c1 = s_kn[dbase + 2][1], c2 = s_kn[dbase + 2][2],
          c3 = s_kn[dbase + 2][3], c4 = s_kn[dbase + 2][4], c5 = s_kn[dbase + 2][5],
          c6 = s_kn[dbase + 2][6];
    float e0 = s_kn[dbase + 3][0], e1 = s_kn[dbase + 3][1], e2 = s_kn[dbase + 3][2],
          e3 = s_kn[dbase + 3][3], e4 = s_kn[dbase + 3][4], e5 = s_kn[dbase + 3][5],
          e6 = s_kn[dbase + 3][6];

    const float4* __restrict__ r0 = &s_T[dbase + 0][0];
    const float4* __restrict__ r1 = &s_T[dbase + 1][0];
    const float4* __restrict__ r2 = &s_T[dbase + 2][0];
    const float4* __restrict__ r3 = &s_T[dbase + 3][0];

    auto evalone = [&](float xx,
                       float k0, float k1, float k2, float k3, float k4, float k5, float k6,
                       const float4* __restrict__ row) -> float {
        int idx = 0;
        idx += (xx >= k0) ? 1 : 0;
        idx += (xx >= k1) ? 1 : 0;
        idx += (xx >= k2) ? 1 : 0;
        idx += (xx >= k3) ? 1 : 0;
        idx += (xx >= k4) ? 1 : 0;
        idx += (xx >= k5) ? 1 : 0;
        idx += (xx >= k6) ? 1 : 0;

        const float4 T = row[idx ^ key];   // one ds_read_b128

        const unsigned u1 = __float_as_uint(T.z);
        const unsigned u2 = __float_as_uint(T.w);
        const float ch = __half2float(__ushort_as_half((unsigned short)(u1 & 0xffffu)));
        const float h  = __half2float(__ushort_as_half((unsigned short)(u1 >> 16)));
        const float d0 = __half2float(__ushort_as_half((unsigned short)(u2 & 0xffffu)));
        const float d1 = __half2float(__ushort_as_half((unsigned short)(u2 >> 16)));

        const float xc    = fminf(fmaxf(xx, -TB), TB);
        const float theta = fmaf(xc, T.x, T.y);
        const float delta = h * T.x;                              // h*invw
        const float B     = h * d0;
        const float A     = fmaf(h, delta, -B);                   // h*(delta-d0)
        const float s2    = (d0 + d1) - (delta + delta);
        const float u     = fmaf(-theta, theta, theta);           // θ(1-θ)
        const float den   = fmaf(s2, u, delta);
        const float rden  = __builtin_amdgcn_rcpf(den);
        const float num1  = theta * fmaf(theta, A, B);
        const float zin   = fmaf(num1, rden, ch);
        const float dmd   = delta - d0;
        const float poly  = fmaf(fmaf(s2, theta, dmd + dmd), theta, d0);
        const float ee    = delta * rden;
        const float larg  = poly * (ee * ee);
        const float lg2   = __log2f(larg);
        // outside [-B,B]: θ∈{0,1} to 1ulp -> larg ~= boundary deriv = 1 -> lg2≈0
        const float z  = (fabsf(xx) <= TB) ? zin : xx;
        const float ld = fmaf(lg2, LN2, -HALF_LOG_2PI);
        return fmaf(z * z, -0.5f, ld);
    };

    const float4* __restrict__ x4 = reinterpret_cast<const float4*>(x);
    float4* __restrict__ o4 = reinterpret_cast<float4*>(out);

    int i = g;
    for (; i + stride < n4; i += 2 * stride) {
        const float4 xa = x4[i];
        const float4 xb = x4[i + stride];
        float4 ra, rb;
        ra.x = evalone(xa.x, a0, a1, a2, a3, a4, a5, a6, r0);
        ra.y = evalone(xa.y, b0, b1, b2, b3, b4, b5, b6, r1);
        ra.z = evalone(xa.z, c0, c1, c2, c3, c4, c5, c6, r2);
        ra.w = evalone(xa.w, e0, e1, e2, e3, e4, e5, e6, r3);
        rb.x = evalone(xb.x, a0, a1, a2, a3, a4, a5, a6, r0);
        rb.y = evalone(xb.y, b0, b1, b2, b3, b4, b5, b6, r1);
        rb.z = evalone(xb.z, c0, c1, c2, c3, c4, c5, c6, r2);
        rb.w = evalone(xb.w, e0, e1, e2, e3, e4, e5, e6, r3);
        o4[i] = ra;
        o4[i + stride] = rb;
    }
    for (; i < n4; i += stride) {
        const float4 xa = x4[i];
        float4 ra;
        ra.x = evalone(xa.x, a0, a1, a2, a3, a4, a5, a6, r0);
        ra.y = evalone(xa.y, b0, b1, b2, b3, b4, b5, b6, r1);
        ra.z = evalone(xa.z, c0, c1, c2, c3, c4, c5, c6, r2);
        ra.w = evalone(xa.w, e0, e1, e2, e3, e4, e5, e6, r3);
        o4[i] = ra;
    }
}

extern "C" void kernel_launch(void* const* d_in, const int* in_sizes, int n_in,
                              void* d_out, int out_size, void* d_ws, size_t ws_size,
                              hipStream_t stream) {
    const float* x  = (const float*)d_in[0];
    const float* uw = (const float*)d_in[1];
    const float* uh = (const float*)d_in[2];
    const float* ud = (const float*)d_in[3];
    float* out = (float*)d_out;

    const int n4 = in_sizes[0] / 4;                 // N*D/4 float4 elements
    int blocks = (n4 + 255) / 256;
    if (blocks > 2048) blocks = 2048;

    mfb_kernel<<<blocks, 256, 0, stream>>>(x, uw, uh, ud, out, n4);
}